// Round 7
// baseline (1487.156 us; speedup 1.0000x reference)
//
#include <hip/hip_runtime.h>

#define N_NODES 50000
#define N_EDGES 1600000
#define HC 128        // H*C == IN
#define LAYERS 3
#define NGRAPH 64
#define OUT_CH 64

// ---------------- zero helpers ----------------
__global__ void zero_f32(float* __restrict__ p, long n) {
    long i = (long)blockIdx.x * blockDim.x + threadIdx.x;
    long stride = (long)gridDim.x * blockDim.x;
    for (; i < n; i += stride) p[i] = 0.f;
}
__global__ void zero_i32(int* __restrict__ p, int n) {
    int i = blockIdx.x * blockDim.x + threadIdx.x;
    int stride = gridDim.x * blockDim.x;
    for (; i < n; i += stride) p[i] = 0;
}

// ---------------- CSR build: histogram -> scan -> scatter ----------------
__global__ void hist_dst(const int* __restrict__ ei, int* __restrict__ cnt) {
    int e = blockIdx.x * blockDim.x + threadIdx.x;
    if (e < N_EDGES) atomicAdd(&cnt[ei[N_EDGES + e]], 1);
}

#define SCAN_T 1024
__global__ __launch_bounds__(SCAN_T) void scan_rowptr(
    const int* __restrict__ cnt, int* __restrict__ rowptr)
{
    __shared__ int part[SCAN_T];
    const int t = threadIdx.x;
    const int CHK = (N_NODES + SCAN_T - 1) / SCAN_T;   // 49
    const int base = t * CHK;
    int s = 0;
    for (int i = 0; i < CHK; ++i) {
        int idx = base + i;
        if (idx < N_NODES) s += cnt[idx];
    }
    part[t] = s;
    __syncthreads();
    for (int off = 1; off < SCAN_T; off <<= 1) {
        int add = (t >= off) ? part[t - off] : 0;
        __syncthreads();
        part[t] += add;
        __syncthreads();
    }
    int run = part[t] - s;   // exclusive prefix of this thread's chunk
    for (int i = 0; i < CHK; ++i) {
        int idx = base + i;
        if (idx < N_NODES) {
            rowptr[idx] = run;
            run += cnt[idx];
        }
    }
    if (t == SCAN_T - 1) rowptr[N_NODES] = part[t];
}

__global__ void scatter_edges(const int* __restrict__ ei,
                              const int* __restrict__ rowptr,
                              int* __restrict__ fill,
                              int* __restrict__ esrc)
{
    int e = blockIdx.x * blockDim.x + threadIdx.x;
    if (e < N_EDGES) {
        int d = ei[N_EDGES + e];
        int pos = rowptr[d] + atomicAdd(&fill[d], 1);
        esrc[pos] = ei[e];
    }
}

// ---------------- fused 4-matrix GEMM: 128-row tile, 8x8 register blocking ---
__global__ __launch_bounds__(256) void gemm4(
    const float* __restrict__ x,
    const float* __restrict__ Wq, const float* __restrict__ bq,
    const float* __restrict__ Wk, const float* __restrict__ bk,
    const float* __restrict__ Wv, const float* __restrict__ bv,
    const float* __restrict__ Wsk, const float* __restrict__ bsk,
    float* __restrict__ oq, float* __restrict__ okv, float* __restrict__ osk)
{
    __shared__ float xs[128][132];   // 67.6 KB; pad 4 floats
    const int bRow = blockIdx.x * 128;
    const int tid = threadIdx.x;

    for (int i = tid; i < 128 * 32; i += 256) {
        int r = i >> 5, c4 = i & 31;
        int gr = bRow + r;
        float4 val = make_float4(0.f, 0.f, 0.f, 0.f);
        if (gr < N_NODES)
            val = *reinterpret_cast<const float4*>(x + (long)gr * HC + c4 * 4);
        *reinterpret_cast<float4*>(&xs[r][c4 * 4]) = val;
    }
    __syncthreads();

    const int rg = tid >> 4;   // 0..15; thread rows rg + 16*i, i=0..7
    const int cg = tid & 15;   // cols cg*8 .. cg*8+7

    const float* Wm[4] = {Wq, Wk, Wv, Wsk};
    const float* bm[4] = {bq, bk, bv, bsk};
    float* ob[4];
    long  os[4];
    ob[0] = oq;       os[0] = HC;
    ob[1] = okv;      os[1] = 2 * HC;
    ob[2] = okv + HC; os[2] = 2 * HC;
    ob[3] = osk;      os[3] = HC;

    #pragma unroll
    for (int m = 0; m < 4; ++m) {
        const float* __restrict__ W = Wm[m];
        const float* __restrict__ b = bm[m];
        float acc[8][8];
        #pragma unroll
        for (int i = 0; i < 8; ++i)
            #pragma unroll
            for (int j = 0; j < 8; ++j) acc[i][j] = b[cg * 8 + j];

        #pragma unroll 2
        for (int kk = 0; kk < 128; ++kk) {
            float4 w0 = *reinterpret_cast<const float4*>(W + kk * HC + cg * 8);
            float4 w1 = *reinterpret_cast<const float4*>(W + kk * HC + cg * 8 + 4);
            float wv[8] = {w0.x, w0.y, w0.z, w0.w, w1.x, w1.y, w1.z, w1.w};
            #pragma unroll
            for (int i = 0; i < 8; ++i) {
                float xv = xs[rg + 16 * i][kk];
                #pragma unroll
                for (int j = 0; j < 8; ++j) acc[i][j] += xv * wv[j];
            }
        }
        float* __restrict__ o = ob[m];
        const long stride = os[m];
        #pragma unroll
        for (int i = 0; i < 8; ++i) {
            int gr = bRow + rg + 16 * i;
            if (gr < N_NODES) {
                float* dst = o + (long)gr * stride + cg * 8;
                *reinterpret_cast<float4*>(dst) =
                    make_float4(acc[i][0], acc[i][1], acc[i][2], acc[i][3]);
                *reinterpret_cast<float4*>(dst + 4) =
                    make_float4(acc[i][4], acc[i][5], acc[i][6], acc[i][7]);
            }
        }
    }
}

// ---------------- fused attention: logits + softmax + aggregate + skip + relu
// One wave per dst node. Lane l owns the adjacent channel pair (2l, 2l+1);
// both channels belong to head h = l>>4, so ONE logit/exp per lane per edge.
// Per edge: two coalesced float2 gathers (k-pair, v-pair) from the 1KB kv
// row; head dot = 4-step shfl_xor butterfly within 16-lane groups; p=exp;
// acc += p*v. 4-edge unroll keeps 8 loads in flight. Softmax by running sum
// (no max-shift: logits are O(1), exp-safe; softmax is shift-invariant).
__global__ __launch_bounds__(256) void edge_attn(
    const float* __restrict__ q, const float* __restrict__ kv,
    const float* __restrict__ skip,
    const int* __restrict__ rowptr, const int* __restrict__ esrc,
    float* __restrict__ xout)
{
    const int lane = threadIdx.x & 63;
    const int node = (int)(((long)blockIdx.x * blockDim.x + threadIdx.x) >> 6);
    if (node >= N_NODES) return;
    const int beg = rowptr[node], end = rowptr[node + 1];
    const long qb = (long)node * HC;
    const float2 qp = *reinterpret_cast<const float2*>(q + qb + 2 * lane);
    const float scale = 0.17677669529663687f;  // 1/sqrt(32)

    float accx = 0.f, accy = 0.f, ps = 0.f;
    int pos = beg;
    for (; pos + 4 <= end; pos += 4) {
        const int s0 = esrc[pos], s1 = esrc[pos + 1];
        const int s2 = esrc[pos + 2], s3 = esrc[pos + 3];
        const float2* r0 = reinterpret_cast<const float2*>(kv + (long)s0 * (2 * HC));
        const float2* r1 = reinterpret_cast<const float2*>(kv + (long)s1 * (2 * HC));
        const float2* r2 = reinterpret_cast<const float2*>(kv + (long)s2 * (2 * HC));
        const float2* r3 = reinterpret_cast<const float2*>(kv + (long)s3 * (2 * HC));
        float2 k0 = r0[lane], k1 = r1[lane], k2 = r2[lane], k3 = r3[lane];
        float2 v0 = r0[64 + lane], v1 = r1[64 + lane];
        float2 v2 = r2[64 + lane], v3 = r3[64 + lane];
        float a0 = qp.x * k0.x + qp.y * k0.y;
        float a1 = qp.x * k1.x + qp.y * k1.y;
        float a2 = qp.x * k2.x + qp.y * k2.y;
        float a3 = qp.x * k3.x + qp.y * k3.y;
        #pragma unroll
        for (int m = 1; m <= 8; m <<= 1) {
            a0 += __shfl_xor(a0, m, 64);
            a1 += __shfl_xor(a1, m, 64);
            a2 += __shfl_xor(a2, m, 64);
            a3 += __shfl_xor(a3, m, 64);
        }
        float p0 = __expf(a0 * scale), p1 = __expf(a1 * scale);
        float p2 = __expf(a2 * scale), p3 = __expf(a3 * scale);
        accx += p0 * v0.x + p1 * v1.x + p2 * v2.x + p3 * v3.x;
        accy += p0 * v0.y + p1 * v1.y + p2 * v2.y + p3 * v3.y;
        ps += p0 + p1 + p2 + p3;
    }
    for (; pos < end; ++pos) {
        const float2* r0 = reinterpret_cast<const float2*>(kv + (long)esrc[pos] * (2 * HC));
        float2 k0 = r0[lane];
        float2 v0 = r0[64 + lane];
        float a0 = qp.x * k0.x + qp.y * k0.y;
        #pragma unroll
        for (int m = 1; m <= 8; m <<= 1) a0 += __shfl_xor(a0, m, 64);
        float p0 = __expf(a0 * scale);
        accx += p0 * v0.x;
        accy += p0 * v0.y;
        ps += p0;
    }
    const float inv = 1.f / (ps + 1e-16f);
    const float2 sk = *reinterpret_cast<const float2*>(skip + qb + 2 * lane);
    float r0 = accx * inv + sk.x;
    float r1 = accy * inv + sk.y;
    float2 res;
    res.x = r0 > 0.f ? r0 : 0.f;
    res.y = r1 > 0.f ? r1 : 0.f;
    *reinterpret_cast<float2*>(xout + qb + 2 * lane) = res;
}

// ---------------- global mean pool: chunked run-length reduction ---------
#define POOL_CHUNK 64
__global__ __launch_bounds__(128) void pool_sum2(
    const float* __restrict__ x, const int* __restrict__ batch,
    float* __restrict__ gsum, float* __restrict__ gcnt)
{
    const int c = threadIdx.x;            // 0..127 (channel)
    const int base = blockIdx.x * POOL_CHUNK;
    if (base >= N_NODES) return;
    const int end = min(base + POOL_CHUNK, N_NODES);
    float acc = 0.f;
    int cnt = 0;
    int curg = batch[base];
    for (int n = base; n < end; ++n) {
        int g = batch[n];
        if (g != curg) {
            atomicAdd(&gsum[curg * HC + c], acc);
            if (c == 0) atomicAdd(&gcnt[curg], (float)cnt);
            acc = 0.f; cnt = 0; curg = g;
        }
        acc += x[(long)n * HC + c];
        cnt++;
    }
    atomicAdd(&gsum[curg * HC + c], acc);
    if (c == 0) atomicAdd(&gcnt[curg], (float)cnt);
}

// ---------------- final FC ----------------
__global__ void final_fc(const float* __restrict__ gsum, const float* __restrict__ gcnt,
                         const float* __restrict__ fcW, const float* __restrict__ fcb,
                         float* __restrict__ out)
{
    int i = blockIdx.x * blockDim.x + threadIdx.x;
    if (i < NGRAPH * OUT_CH) {
        int g = i >> 6, o = i & 63;
        float cnt = gcnt[g];
        cnt = cnt > 1.f ? cnt : 1.f;
        float inv = 1.f / cnt;
        float accv = fcb[o];
        for (int c = 0; c < HC; ++c)
            accv += (gsum[g * HC + c] * inv) * fcW[c * OUT_CH + o];
        out[i] = accv;
    }
}

extern "C" void kernel_launch(void* const* d_in, const int* in_sizes, int n_in,
                              void* d_out, int out_size, void* d_ws, size_t ws_size,
                              hipStream_t stream)
{
    const float* x0   = (const float*)d_in[0];
    const int*   ei   = (const int*)d_in[1];
    const int*   batch= (const int*)d_in[2];
    const float* Wq   = (const float*)d_in[3];
    const float* bq   = (const float*)d_in[4];
    const float* Wk   = (const float*)d_in[5];
    const float* bk   = (const float*)d_in[6];
    const float* Wv   = (const float*)d_in[7];
    const float* bv   = (const float*)d_in[8];
    const float* Wsk  = (const float*)d_in[9];
    const float* bsk  = (const float*)d_in[10];
    const float* fcW  = (const float*)d_in[11];
    const float* fcb  = (const float*)d_in[12];
    float* out = (float*)d_out;

    const long NH = (long)N_NODES * HC;   // 6.4M floats
    float* ws   = (float*)d_ws;
    float* q    = ws;                    // NH
    float* kv   = q + NH;                // 2*NH  (k|v interleaved per node)
    float* skip = kv + 2 * NH;           // NH
    float* xA   = skip + NH;             // NH
    float* gsum = xA + NH;               // G*HC
    float* gcnt = gsum + NGRAPH * HC;    // G
    int*   iws  = (int*)(gcnt + NGRAPH);
    int*   rowptr = iws;                 // N+1
    int*   cnt    = rowptr + (N_NODES + 1);  // N (reused as fill)
    int*   esrc   = cnt + N_NODES;       // E

    const int gemmGrid = (N_NODES + 127) / 128;                   // 391
    const int eGrid    = (N_EDGES + 255) / 256;                   // 6250
    const int nodeGrid = (N_NODES + 3) / 4;                       // 12500 (4 waves/block)

    // ---- CSR build (edge_index is layer-invariant) ----
    zero_i32<<<256, 256, 0, stream>>>(cnt, N_NODES);
    hist_dst<<<eGrid, 256, 0, stream>>>(ei, cnt);
    scan_rowptr<<<1, SCAN_T, 0, stream>>>(cnt, rowptr);
    zero_i32<<<256, 256, 0, stream>>>(cnt, N_NODES);   // reuse as fill
    scatter_edges<<<eGrid, 256, 0, stream>>>(ei, rowptr, cnt, esrc);

    // ---- layers ----
    const float* xin = x0;
    for (int l = 0; l < LAYERS; ++l) {
        const long wOff = (long)l * HC * HC;
        const long bOff = (long)l * HC;
        gemm4<<<gemmGrid, 256, 0, stream>>>(xin,
            Wq + wOff, bq + bOff, Wk + wOff, bk + bOff,
            Wv + wOff, bv + bOff, Wsk + wOff, bsk + bOff,
            q, kv, skip);
        edge_attn<<<nodeGrid, 256, 0, stream>>>(q, kv, skip, rowptr, esrc, xA);
        xin = xA;
    }

    // ---- pooling + fc ----
    zero_f32<<<64, 256, 0, stream>>>(gsum, (long)NGRAPH * HC + NGRAPH);
    pool_sum2<<<(N_NODES + POOL_CHUNK - 1) / POOL_CHUNK, 128, 0, stream>>>(xin, batch, gsum, gcnt);
    final_fc<<<(NGRAPH * OUT_CH + 255) / 256, 256, 0, stream>>>(gsum, gcnt, fcW, fcb, out);
}

// Round 8
// 1451.313 us; speedup vs baseline: 1.0247x; 1.0247x over previous
//
#include <hip/hip_runtime.h>

#define N_NODES 50000
#define N_EDGES 1600000
#define HC 128        // H*C == IN
#define LAYERS 3
#define NGRAPH 64
#define OUT_CH 64

// ---------------- zero helpers ----------------
__global__ void zero_f32(float* __restrict__ p, long n) {
    long i = (long)blockIdx.x * blockDim.x + threadIdx.x;
    long stride = (long)gridDim.x * blockDim.x;
    for (; i < n; i += stride) p[i] = 0.f;
}
__global__ void zero_i32(int* __restrict__ p, int n) {
    int i = blockIdx.x * blockDim.x + threadIdx.x;
    int stride = gridDim.x * blockDim.x;
    for (; i < n; i += stride) p[i] = 0;
}

// ---------------- CSR build: histogram -> scan -> scatter ----------------
__global__ void hist_dst(const int* __restrict__ ei, int* __restrict__ cnt) {
    int e = blockIdx.x * blockDim.x + threadIdx.x;
    if (e < N_EDGES) atomicAdd(&cnt[ei[N_EDGES + e]], 1);
}

#define SCAN_T 1024
__global__ __launch_bounds__(SCAN_T) void scan_rowptr(
    const int* __restrict__ cnt, int* __restrict__ rowptr)
{
    __shared__ int part[SCAN_T];
    const int t = threadIdx.x;
    const int CHK = (N_NODES + SCAN_T - 1) / SCAN_T;   // 49
    const int base = t * CHK;
    int s = 0;
    for (int i = 0; i < CHK; ++i) {
        int idx = base + i;
        if (idx < N_NODES) s += cnt[idx];
    }
    part[t] = s;
    __syncthreads();
    for (int off = 1; off < SCAN_T; off <<= 1) {
        int add = (t >= off) ? part[t - off] : 0;
        __syncthreads();
        part[t] += add;
        __syncthreads();
    }
    int run = part[t] - s;   // exclusive prefix of this thread's chunk
    for (int i = 0; i < CHK; ++i) {
        int idx = base + i;
        if (idx < N_NODES) {
            rowptr[idx] = run;
            run += cnt[idx];
        }
    }
    if (t == SCAN_T - 1) rowptr[N_NODES] = part[t];
}

__global__ void scatter_edges(const int* __restrict__ ei,
                              const int* __restrict__ rowptr,
                              int* __restrict__ fill,
                              int* __restrict__ esrc)
{
    int e = blockIdx.x * blockDim.x + threadIdx.x;
    if (e < N_EDGES) {
        int d = ei[N_EDGES + e];
        int pos = rowptr[d] + atomicAdd(&fill[d], 1);
        esrc[pos] = ei[e];
    }
}

// ---------------- fused 4-matrix GEMM: 64-row tile, 4x8 register blocking ---
// 33.8 KB LDS -> 4 blocks/CU (4 waves/SIMD) for latency hiding.
// out layouts: q [N][128]; kv [N][256] (k 0..127, v 128..255); skip [N][128].
__global__ __launch_bounds__(256) void gemm4(
    const float* __restrict__ x,
    const float* __restrict__ Wq, const float* __restrict__ bq,
    const float* __restrict__ Wk, const float* __restrict__ bk,
    const float* __restrict__ Wv, const float* __restrict__ bv,
    const float* __restrict__ Wsk, const float* __restrict__ bsk,
    float* __restrict__ oq, float* __restrict__ okv, float* __restrict__ osk)
{
    __shared__ float xs[64][132];   // 33.8 KB; pad 4 floats
    const int bRow = blockIdx.x * 64;
    const int tid = threadIdx.x;

    for (int i = tid; i < 64 * 32; i += 256) {
        int r = i >> 5, c4 = i & 31;
        int gr = bRow + r;
        float4 val = make_float4(0.f, 0.f, 0.f, 0.f);
        if (gr < N_NODES)
            val = *reinterpret_cast<const float4*>(x + (long)gr * HC + c4 * 4);
        *reinterpret_cast<float4*>(&xs[r][c4 * 4]) = val;
    }
    __syncthreads();

    const int rg = tid >> 4;   // 0..15; rows rg + 16*i, i=0..3
    const int cg = tid & 15;   // cols cg*8 .. cg*8+7

    const float* Wm[4] = {Wq, Wk, Wv, Wsk};
    const float* bm[4] = {bq, bk, bv, bsk};
    float* ob[4];
    long  os[4];
    ob[0] = oq;       os[0] = HC;
    ob[1] = okv;      os[1] = 2 * HC;
    ob[2] = okv + HC; os[2] = 2 * HC;
    ob[3] = osk;      os[3] = HC;

    #pragma unroll
    for (int m = 0; m < 4; ++m) {
        const float* __restrict__ W = Wm[m];
        const float* __restrict__ b = bm[m];
        float acc[4][8];
        #pragma unroll
        for (int i = 0; i < 4; ++i)
            #pragma unroll
            for (int j = 0; j < 8; ++j) acc[i][j] = b[cg * 8 + j];

        #pragma unroll 2
        for (int kk = 0; kk < 128; ++kk) {
            float4 w0 = *reinterpret_cast<const float4*>(W + kk * HC + cg * 8);
            float4 w1 = *reinterpret_cast<const float4*>(W + kk * HC + cg * 8 + 4);
            float wv[8] = {w0.x, w0.y, w0.z, w0.w, w1.x, w1.y, w1.z, w1.w};
            #pragma unroll
            for (int i = 0; i < 4; ++i) {
                float xv = xs[rg + 16 * i][kk];
                #pragma unroll
                for (int j = 0; j < 8; ++j) acc[i][j] += xv * wv[j];
            }
        }
        float* __restrict__ o = ob[m];
        const long stride = os[m];
        #pragma unroll
        for (int i = 0; i < 4; ++i) {
            int gr = bRow + rg + 16 * i;
            if (gr < N_NODES) {
                float* dst = o + (long)gr * stride + cg * 8;
                *reinterpret_cast<float4*>(dst) =
                    make_float4(acc[i][0], acc[i][1], acc[i][2], acc[i][3]);
                *reinterpret_cast<float4*>(dst + 4) =
                    make_float4(acc[i][4], acc[i][5], acc[i][6], acc[i][7]);
            }
        }
    }
}

// ---------------- fused attention: logits + softmax + aggregate + skip + relu
// One wave per dst node. Lane l owns channel pair (2l, 2l+1), head = l>>4.
// 6-edge unroll: 12 float2 gathers in flight per wave (latency/MLP-bound
// kernel -> more outstanding misses). One butterfly+exp per lane per edge.
__global__ __launch_bounds__(256) void edge_attn(
    const float* __restrict__ q, const float* __restrict__ kv,
    const float* __restrict__ skip,
    const int* __restrict__ rowptr, const int* __restrict__ esrc,
    float* __restrict__ xout)
{
    const int lane = threadIdx.x & 63;
    const int node = (int)(((long)blockIdx.x * blockDim.x + threadIdx.x) >> 6);
    if (node >= N_NODES) return;
    const int beg = rowptr[node], end = rowptr[node + 1];
    const long qb = (long)node * HC;
    const float2 qp = *reinterpret_cast<const float2*>(q + qb + 2 * lane);
    const float scale = 0.17677669529663687f;  // 1/sqrt(32)

    float accx = 0.f, accy = 0.f, ps = 0.f;
    int pos = beg;
    for (; pos + 6 <= end; pos += 6) {
        int s[6];
        #pragma unroll
        for (int u = 0; u < 6; ++u) s[u] = esrc[pos + u];
        float2 kk[6], vv[6];
        #pragma unroll
        for (int u = 0; u < 6; ++u) {
            const float2* r = reinterpret_cast<const float2*>(kv + (long)s[u] * (2 * HC));
            kk[u] = r[lane];
            vv[u] = r[64 + lane];
        }
        float a[6];
        #pragma unroll
        for (int u = 0; u < 6; ++u) a[u] = qp.x * kk[u].x + qp.y * kk[u].y;
        #pragma unroll
        for (int m = 1; m <= 8; m <<= 1) {
            #pragma unroll
            for (int u = 0; u < 6; ++u) a[u] += __shfl_xor(a[u], m, 64);
        }
        #pragma unroll
        for (int u = 0; u < 6; ++u) {
            float p = __expf(a[u] * scale);
            accx += p * vv[u].x;
            accy += p * vv[u].y;
            ps += p;
        }
    }
    for (; pos + 2 <= end; pos += 2) {
        const float2* r0 = reinterpret_cast<const float2*>(kv + (long)esrc[pos] * (2 * HC));
        const float2* r1 = reinterpret_cast<const float2*>(kv + (long)esrc[pos + 1] * (2 * HC));
        float2 k0 = r0[lane], k1 = r1[lane];
        float2 v0 = r0[64 + lane], v1 = r1[64 + lane];
        float a0 = qp.x * k0.x + qp.y * k0.y;
        float a1 = qp.x * k1.x + qp.y * k1.y;
        #pragma unroll
        for (int m = 1; m <= 8; m <<= 1) {
            a0 += __shfl_xor(a0, m, 64);
            a1 += __shfl_xor(a1, m, 64);
        }
        float p0 = __expf(a0 * scale), p1 = __expf(a1 * scale);
        accx += p0 * v0.x + p1 * v1.x;
        accy += p0 * v0.y + p1 * v1.y;
        ps += p0 + p1;
    }
    if (pos < end) {
        const float2* r0 = reinterpret_cast<const float2*>(kv + (long)esrc[pos] * (2 * HC));
        float2 k0 = r0[lane];
        float2 v0 = r0[64 + lane];
        float a0 = qp.x * k0.x + qp.y * k0.y;
        #pragma unroll
        for (int m = 1; m <= 8; m <<= 1) a0 += __shfl_xor(a0, m, 64);
        float p0 = __expf(a0 * scale);
        accx += p0 * v0.x;
        accy += p0 * v0.y;
        ps += p0;
    }
    const float inv = 1.f / (ps + 1e-16f);
    const float2 sk = *reinterpret_cast<const float2*>(skip + qb + 2 * lane);
    float r0 = accx * inv + sk.x;
    float r1 = accy * inv + sk.y;
    float2 res;
    res.x = r0 > 0.f ? r0 : 0.f;
    res.y = r1 > 0.f ? r1 : 0.f;
    *reinterpret_cast<float2*>(xout + qb + 2 * lane) = res;
}

// ---------------- global mean pool: chunked run-length reduction ---------
#define POOL_CHUNK 64
__global__ __launch_bounds__(128) void pool_sum2(
    const float* __restrict__ x, const int* __restrict__ batch,
    float* __restrict__ gsum, float* __restrict__ gcnt)
{
    const int c = threadIdx.x;            // 0..127 (channel)
    const int base = blockIdx.x * POOL_CHUNK;
    if (base >= N_NODES) return;
    const int end = min(base + POOL_CHUNK, N_NODES);
    float acc = 0.f;
    int cnt = 0;
    int curg = batch[base];
    for (int n = base; n < end; ++n) {
        int g = batch[n];
        if (g != curg) {
            atomicAdd(&gsum[curg * HC + c], acc);
            if (c == 0) atomicAdd(&gcnt[curg], (float)cnt);
            acc = 0.f; cnt = 0; curg = g;
        }
        acc += x[(long)n * HC + c];
        cnt++;
    }
    atomicAdd(&gsum[curg * HC + c], acc);
    if (c == 0) atomicAdd(&gcnt[curg], (float)cnt);
}

// ---------------- final FC ----------------
__global__ void final_fc(const float* __restrict__ gsum, const float* __restrict__ gcnt,
                         const float* __restrict__ fcW, const float* __restrict__ fcb,
                         float* __restrict__ out)
{
    int i = blockIdx.x * blockDim.x + threadIdx.x;
    if (i < NGRAPH * OUT_CH) {
        int g = i >> 6, o = i & 63;
        float cnt = gcnt[g];
        cnt = cnt > 1.f ? cnt : 1.f;
        float inv = 1.f / cnt;
        float accv = fcb[o];
        for (int c = 0; c < HC; ++c)
            accv += (gsum[g * HC + c] * inv) * fcW[c * OUT_CH + o];
        out[i] = accv;
    }
}

extern "C" void kernel_launch(void* const* d_in, const int* in_sizes, int n_in,
                              void* d_out, int out_size, void* d_ws, size_t ws_size,
                              hipStream_t stream)
{
    const float* x0   = (const float*)d_in[0];
    const int*   ei   = (const int*)d_in[1];
    const int*   batch= (const int*)d_in[2];
    const float* Wq   = (const float*)d_in[3];
    const float* bq   = (const float*)d_in[4];
    const float* Wk   = (const float*)d_in[5];
    const float* bk   = (const float*)d_in[6];
    const float* Wv   = (const float*)d_in[7];
    const float* bv   = (const float*)d_in[8];
    const float* Wsk  = (const float*)d_in[9];
    const float* bsk  = (const float*)d_in[10];
    const float* fcW  = (const float*)d_in[11];
    const float* fcb  = (const float*)d_in[12];
    float* out = (float*)d_out;

    const long NH = (long)N_NODES * HC;   // 6.4M floats
    float* ws   = (float*)d_ws;
    float* q    = ws;                    // NH
    float* kv   = q + NH;                // 2*NH  (k|v interleaved per node)
    float* skip = kv + 2 * NH;           // NH
    float* xA   = skip + NH;             // NH
    float* gsum = xA + NH;               // G*HC
    float* gcnt = gsum + NGRAPH * HC;    // G
    int*   iws  = (int*)(gcnt + NGRAPH);
    int*   rowptr = iws;                 // N+1
    int*   cnt    = rowptr + (N_NODES + 1);  // N (reused as fill)
    int*   esrc   = cnt + N_NODES;       // E

    const int gemmGrid = (N_NODES + 63) / 64;                     // 782
    const int eGrid    = (N_EDGES + 255) / 256;                   // 6250
    const int nodeGrid = (N_NODES + 3) / 4;                       // 12500 (4 waves/block)

    // ---- CSR build (edge_index is layer-invariant) ----
    zero_i32<<<256, 256, 0, stream>>>(cnt, N_NODES);
    hist_dst<<<eGrid, 256, 0, stream>>>(ei, cnt);
    scan_rowptr<<<1, SCAN_T, 0, stream>>>(cnt, rowptr);
    zero_i32<<<256, 256, 0, stream>>>(cnt, N_NODES);   // reuse as fill
    scatter_edges<<<eGrid, 256, 0, stream>>>(ei, rowptr, cnt, esrc);

    // ---- layers ----
    const float* xin = x0;
    for (int l = 0; l < LAYERS; ++l) {
        const long wOff = (long)l * HC * HC;
        const long bOff = (long)l * HC;
        gemm4<<<gemmGrid, 256, 0, stream>>>(xin,
            Wq + wOff, bq + bOff, Wk + wOff, bk + bOff,
            Wv + wOff, bv + bOff, Wsk + wOff, bsk + bOff,
            q, kv, skip);
        edge_attn<<<nodeGrid, 256, 0, stream>>>(q, kv, skip, rowptr, esrc, xA);
        xin = xA;
    }

    // ---- pooling + fc ----
    zero_f32<<<64, 256, 0, stream>>>(gsum, (long)NGRAPH * HC + NGRAPH);
    pool_sum2<<<(N_NODES + POOL_CHUNK - 1) / POOL_CHUNK, 128, 0, stream>>>(xin, batch, gsum, gcnt);
    final_fc<<<(NGRAPH * OUT_CH + 255) / 256, 256, 0, stream>>>(gsum, gcnt, fcW, fcb, out);
}

// Round 9
// 1186.056 us; speedup vs baseline: 1.2539x; 1.2236x over previous
//
#include <hip/hip_runtime.h>
#include <hip/hip_fp16.h>

#define N_NODES 50000
#define N_EDGES 1600000
#define HC 128        // H*C == IN
#define LAYERS 3
#define NGRAPH 64
#define OUT_CH 64

// ---------------- zero helpers ----------------
__global__ void zero_f32(float* __restrict__ p, long n) {
    long i = (long)blockIdx.x * blockDim.x + threadIdx.x;
    long stride = (long)gridDim.x * blockDim.x;
    for (; i < n; i += stride) p[i] = 0.f;
}
__global__ void zero_i32(int* __restrict__ p, int n) {
    int i = blockIdx.x * blockDim.x + threadIdx.x;
    int stride = gridDim.x * blockDim.x;
    for (; i < n; i += stride) p[i] = 0;
}

// ---------------- CSR build: histogram -> scan -> scatter ----------------
__global__ void hist_dst(const int* __restrict__ ei, int* __restrict__ cnt) {
    int e = blockIdx.x * blockDim.x + threadIdx.x;
    if (e < N_EDGES) atomicAdd(&cnt[ei[N_EDGES + e]], 1);
}

#define SCAN_T 1024
__global__ __launch_bounds__(SCAN_T) void scan_rowptr(
    const int* __restrict__ cnt, int* __restrict__ rowptr)
{
    __shared__ int part[SCAN_T];
    const int t = threadIdx.x;
    const int CHK = (N_NODES + SCAN_T - 1) / SCAN_T;   // 49
    const int base = t * CHK;
    int s = 0;
    for (int i = 0; i < CHK; ++i) {
        int idx = base + i;
        if (idx < N_NODES) s += cnt[idx];
    }
    part[t] = s;
    __syncthreads();
    for (int off = 1; off < SCAN_T; off <<= 1) {
        int add = (t >= off) ? part[t - off] : 0;
        __syncthreads();
        part[t] += add;
        __syncthreads();
    }
    int run = part[t] - s;   // exclusive prefix of this thread's chunk
    for (int i = 0; i < CHK; ++i) {
        int idx = base + i;
        if (idx < N_NODES) {
            rowptr[idx] = run;
            run += cnt[idx];
        }
    }
    if (t == SCAN_T - 1) rowptr[N_NODES] = part[t];
}

__global__ void scatter_edges(const int* __restrict__ ei,
                              const int* __restrict__ rowptr,
                              int* __restrict__ fill,
                              int* __restrict__ esrc)
{
    int e = blockIdx.x * blockDim.x + threadIdx.x;
    if (e < N_EDGES) {
        int d = ei[N_EDGES + e];
        int pos = rowptr[d] + atomicAdd(&fill[d], 1);
        esrc[pos] = ei[e];
    }
}

// ---------------- fused 4-matrix GEMM: 64-row tile, 4x8 register blocking ---
// Outputs: q [N][128] f32; skip [N][128] f32; kv [N][256] __half interleaved:
// group j (8 B) = [k_{2j}, k_{2j+1}, v_{2j}, v_{2j+1}]  -> one 8 B load per
// lane per edge in edge_attn.
__global__ __launch_bounds__(256) void gemm4(
    const float* __restrict__ x,
    const float* __restrict__ Wq, const float* __restrict__ bq,
    const float* __restrict__ Wk, const float* __restrict__ bk,
    const float* __restrict__ Wv, const float* __restrict__ bv,
    const float* __restrict__ Wsk, const float* __restrict__ bsk,
    float* __restrict__ oq, __half* __restrict__ okv, float* __restrict__ osk)
{
    __shared__ float xs[64][132];   // 33.8 KB; pad 4 floats
    const int bRow = blockIdx.x * 64;
    const int tid = threadIdx.x;

    for (int i = tid; i < 64 * 32; i += 256) {
        int r = i >> 5, c4 = i & 31;
        int gr = bRow + r;
        float4 val = make_float4(0.f, 0.f, 0.f, 0.f);
        if (gr < N_NODES)
            val = *reinterpret_cast<const float4*>(x + (long)gr * HC + c4 * 4);
        *reinterpret_cast<float4*>(&xs[r][c4 * 4]) = val;
    }
    __syncthreads();

    const int rg = tid >> 4;   // 0..15; rows rg + 16*i, i=0..3
    const int cg = tid & 15;   // cols cg*8 .. cg*8+7

    const float* Wm[4] = {Wq, Wk, Wv, Wsk};
    const float* bm[4] = {bq, bk, bv, bsk};

    #pragma unroll
    for (int m = 0; m < 4; ++m) {
        const float* __restrict__ W = Wm[m];
        const float* __restrict__ b = bm[m];
        float acc[4][8];
        #pragma unroll
        for (int i = 0; i < 4; ++i)
            #pragma unroll
            for (int j = 0; j < 8; ++j) acc[i][j] = b[cg * 8 + j];

        #pragma unroll 2
        for (int kk = 0; kk < 128; ++kk) {
            float4 w0 = *reinterpret_cast<const float4*>(W + kk * HC + cg * 8);
            float4 w1 = *reinterpret_cast<const float4*>(W + kk * HC + cg * 8 + 4);
            float wv[8] = {w0.x, w0.y, w0.z, w0.w, w1.x, w1.y, w1.z, w1.w};
            #pragma unroll
            for (int i = 0; i < 4; ++i) {
                float xv = xs[rg + 16 * i][kk];
                #pragma unroll
                for (int j = 0; j < 8; ++j) acc[i][j] += xv * wv[j];
            }
        }
        #pragma unroll
        for (int i = 0; i < 4; ++i) {
            int gr = bRow + rg + 16 * i;
            if (gr >= N_NODES) continue;
            if (m == 0 || m == 3) {
                float* o = (m == 0) ? oq : osk;
                float* dst = o + (long)gr * HC + cg * 8;
                *reinterpret_cast<float4*>(dst) =
                    make_float4(acc[i][0], acc[i][1], acc[i][2], acc[i][3]);
                *reinterpret_cast<float4*>(dst + 4) =
                    make_float4(acc[i][4], acc[i][5], acc[i][6], acc[i][7]);
            } else {
                // k -> slot 0 of each 4-half group; v -> slot 1 (as __half2)
                const int vOff = (m == 2) ? 1 : 0;
                __half2* dst2 = reinterpret_cast<__half2*>(okv + (long)gr * 256);
                #pragma unroll
                for (int t = 0; t < 4; ++t)
                    dst2[(4 * cg + t) * 2 + vOff] =
                        __floats2half2_rn(acc[i][2 * t], acc[i][2 * t + 1]);
            }
        }
    }
}

// ---------------- fused attention: logits + softmax + aggregate + skip + relu
// One wave per dst node. Lane l owns channel pair (2l, 2l+1), head = l>>4.
// Per edge per lane: ONE 8 B load (uint2) = [k-pair | v-pair] fp16. Head dot
// via 4-step shfl_xor butterfly over 16-lane groups; p=exp; acc += p*v.
// Softmax by running sum (logits O(1), exp-safe; shift-invariant => exact).
__global__ __launch_bounds__(256) void edge_attn(
    const float* __restrict__ q, const __half* __restrict__ kv,
    const float* __restrict__ skip,
    const int* __restrict__ rowptr, const int* __restrict__ esrc,
    float* __restrict__ xout)
{
    const int lane = threadIdx.x & 63;
    const int node = (int)(((long)blockIdx.x * blockDim.x + threadIdx.x) >> 6);
    if (node >= N_NODES) return;
    const int beg = rowptr[node], end = rowptr[node + 1];
    const long qb = (long)node * HC;
    const float2 qp = *reinterpret_cast<const float2*>(q + qb + 2 * lane);
    const float scale = 0.17677669529663687f;  // 1/sqrt(32)

    float accx = 0.f, accy = 0.f, ps = 0.f;
    int pos = beg;
    for (; pos + 6 <= end; pos += 6) {
        uint2 d[6];
        #pragma unroll
        for (int u = 0; u < 6; ++u) {
            const uint2* r = reinterpret_cast<const uint2*>(kv + (long)esrc[pos + u] * 256);
            d[u] = r[lane];
        }
        float a[6];
        float2 vf[6];
        #pragma unroll
        for (int u = 0; u < 6; ++u) {
            float2 kf = __half22float2(*reinterpret_cast<__half2*>(&d[u].x));
            vf[u] = __half22float2(*reinterpret_cast<__half2*>(&d[u].y));
            a[u] = qp.x * kf.x + qp.y * kf.y;
        }
        #pragma unroll
        for (int m = 1; m <= 8; m <<= 1) {
            #pragma unroll
            for (int u = 0; u < 6; ++u) a[u] += __shfl_xor(a[u], m, 64);
        }
        #pragma unroll
        for (int u = 0; u < 6; ++u) {
            float p = __expf(a[u] * scale);
            accx += p * vf[u].x;
            accy += p * vf[u].y;
            ps += p;
        }
    }
    for (; pos < end; ++pos) {
        const uint2* r = reinterpret_cast<const uint2*>(kv + (long)esrc[pos] * 256);
        uint2 dd = r[lane];
        float2 kf = __half22float2(*reinterpret_cast<__half2*>(&dd.x));
        float2 vv = __half22float2(*reinterpret_cast<__half2*>(&dd.y));
        float a0 = qp.x * kf.x + qp.y * kf.y;
        #pragma unroll
        for (int m = 1; m <= 8; m <<= 1) a0 += __shfl_xor(a0, m, 64);
        float p0 = __expf(a0 * scale);
        accx += p0 * vv.x;
        accy += p0 * vv.y;
        ps += p0;
    }
    const float inv = 1.f / (ps + 1e-16f);
    const float2 sk = *reinterpret_cast<const float2*>(skip + qb + 2 * lane);
    float r0 = accx * inv + sk.x;
    float r1 = accy * inv + sk.y;
    float2 res;
    res.x = r0 > 0.f ? r0 : 0.f;
    res.y = r1 > 0.f ? r1 : 0.f;
    *reinterpret_cast<float2*>(xout + qb + 2 * lane) = res;
}

// ---------------- global mean pool: chunked run-length reduction ---------
#define POOL_CHUNK 64
__global__ __launch_bounds__(128) void pool_sum2(
    const float* __restrict__ x, const int* __restrict__ batch,
    float* __restrict__ gsum, float* __restrict__ gcnt)
{
    const int c = threadIdx.x;            // 0..127 (channel)
    const int base = blockIdx.x * POOL_CHUNK;
    if (base >= N_NODES) return;
    const int end = min(base + POOL_CHUNK, N_NODES);
    float acc = 0.f;
    int cnt = 0;
    int curg = batch[base];
    for (int n = base; n < end; ++n) {
        int g = batch[n];
        if (g != curg) {
            atomicAdd(&gsum[curg * HC + c], acc);
            if (c == 0) atomicAdd(&gcnt[curg], (float)cnt);
            acc = 0.f; cnt = 0; curg = g;
        }
        acc += x[(long)n * HC + c];
        cnt++;
    }
    atomicAdd(&gsum[curg * HC + c], acc);
    if (c == 0) atomicAdd(&gcnt[curg], (float)cnt);
}

// ---------------- final FC ----------------
__global__ void final_fc(const float* __restrict__ gsum, const float* __restrict__ gcnt,
                         const float* __restrict__ fcW, const float* __restrict__ fcb,
                         float* __restrict__ out)
{
    int i = blockIdx.x * blockDim.x + threadIdx.x;
    if (i < NGRAPH * OUT_CH) {
        int g = i >> 6, o = i & 63;
        float cnt = gcnt[g];
        cnt = cnt > 1.f ? cnt : 1.f;
        float inv = 1.f / cnt;
        float accv = fcb[o];
        for (int c = 0; c < HC; ++c)
            accv += (gsum[g * HC + c] * inv) * fcW[c * OUT_CH + o];
        out[i] = accv;
    }
}

extern "C" void kernel_launch(void* const* d_in, const int* in_sizes, int n_in,
                              void* d_out, int out_size, void* d_ws, size_t ws_size,
                              hipStream_t stream)
{
    const float* x0   = (const float*)d_in[0];
    const int*   ei   = (const int*)d_in[1];
    const int*   batch= (const int*)d_in[2];
    const float* Wq   = (const float*)d_in[3];
    const float* bq   = (const float*)d_in[4];
    const float* Wk   = (const float*)d_in[5];
    const float* bk   = (const float*)d_in[6];
    const float* Wv   = (const float*)d_in[7];
    const float* bv   = (const float*)d_in[8];
    const float* Wsk  = (const float*)d_in[9];
    const float* bsk  = (const float*)d_in[10];
    const float* fcW  = (const float*)d_in[11];
    const float* fcb  = (const float*)d_in[12];
    float* out = (float*)d_out;

    const long NH = (long)N_NODES * HC;   // 6.4M floats
    float* ws   = (float*)d_ws;
    float* q    = ws;                    // NH floats
    float* skip = q + NH;                // NH floats
    float* xA   = skip + NH;             // NH floats
    float* gsum = xA + NH;               // G*HC
    float* gcnt = gsum + NGRAPH * HC;    // G
    __half* kvh = (__half*)(gcnt + NGRAPH);          // N*256 halfs (25.6 MB)
    int*   iws  = (int*)(kvh + (long)N_NODES * 256);
    int*   rowptr = iws;                 // N+1
    int*   cnt    = rowptr + (N_NODES + 1);  // N (reused as fill)
    int*   esrc   = cnt + N_NODES;       // E

    const int gemmGrid = (N_NODES + 63) / 64;                     // 782
    const int eGrid    = (N_EDGES + 255) / 256;                   // 6250
    const int nodeGrid = (N_NODES + 3) / 4;                       // 12500 (4 waves/block)

    // ---- CSR build (edge_index is layer-invariant) ----
    zero_i32<<<256, 256, 0, stream>>>(cnt, N_NODES);
    hist_dst<<<eGrid, 256, 0, stream>>>(ei, cnt);
    scan_rowptr<<<1, SCAN_T, 0, stream>>>(cnt, rowptr);
    zero_i32<<<256, 256, 0, stream>>>(cnt, N_NODES);   // reuse as fill
    scatter_edges<<<eGrid, 256, 0, stream>>>(ei, rowptr, cnt, esrc);

    // ---- layers ----
    const float* xin = x0;
    for (int l = 0; l < LAYERS; ++l) {
        const long wOff = (long)l * HC * HC;
        const long bOff = (long)l * HC;
        gemm4<<<gemmGrid, 256, 0, stream>>>(xin,
            Wq + wOff, bq + bOff, Wk + wOff, bk + bOff,
            Wv + wOff, bv + bOff, Wsk + wOff, bsk + bOff,
            q, kvh, skip);
        edge_attn<<<nodeGrid, 256, 0, stream>>>(q, kvh, skip, rowptr, esrc, xA);
        xin = xA;
    }

    // ---- pooling + fc ----
    zero_f32<<<64, 256, 0, stream>>>(gsum, (long)NGRAPH * HC + NGRAPH);
    pool_sum2<<<(N_NODES + POOL_CHUNK - 1) / POOL_CHUNK, 128, 0, stream>>>(xin, batch, gsum, gcnt);
    final_fc<<<(NGRAPH * OUT_CH + 255) / 256, 256, 0, stream>>>(gsum, gcnt, fcW, fcb, out);
}

// Round 10
// 811.953 us; speedup vs baseline: 1.8316x; 1.4607x over previous
//
#include <hip/hip_runtime.h>
#include <hip/hip_fp16.h>

#define N_NODES 50000
#define N_EDGES 1600000
#define HC 128        // H*C == IN
#define LAYERS 3
#define NGRAPH 64
#define OUT_CH 64

typedef _Float16 half8 __attribute__((ext_vector_type(8)));
typedef float f32x4 __attribute__((ext_vector_type(4)));

// ---------------- zero helpers ----------------
__global__ void zero_f32(float* __restrict__ p, long n) {
    long i = (long)blockIdx.x * blockDim.x + threadIdx.x;
    long stride = (long)gridDim.x * blockDim.x;
    for (; i < n; i += stride) p[i] = 0.f;
}
__global__ void zero_i32(int* __restrict__ p, int n) {
    int i = blockIdx.x * blockDim.x + threadIdx.x;
    int stride = gridDim.x * blockDim.x;
    for (; i < n; i += stride) p[i] = 0;
}

// ---------------- CSR build: histogram -> scan -> scatter ----------------
__global__ void hist_dst(const int* __restrict__ ei, int* __restrict__ cnt) {
    int e = blockIdx.x * blockDim.x + threadIdx.x;
    if (e < N_EDGES) atomicAdd(&cnt[ei[N_EDGES + e]], 1);
}

#define SCAN_T 1024
__global__ __launch_bounds__(SCAN_T) void scan_rowptr(
    const int* __restrict__ cnt, int* __restrict__ rowptr)
{
    __shared__ int part[SCAN_T];
    const int t = threadIdx.x;
    const int CHK = (N_NODES + SCAN_T - 1) / SCAN_T;   // 49
    const int base = t * CHK;
    int s = 0;
    for (int i = 0; i < CHK; ++i) {
        int idx = base + i;
        if (idx < N_NODES) s += cnt[idx];
    }
    part[t] = s;
    __syncthreads();
    for (int off = 1; off < SCAN_T; off <<= 1) {
        int add = (t >= off) ? part[t - off] : 0;
        __syncthreads();
        part[t] += add;
        __syncthreads();
    }
    int run = part[t] - s;   // exclusive prefix of this thread's chunk
    for (int i = 0; i < CHK; ++i) {
        int idx = base + i;
        if (idx < N_NODES) {
            rowptr[idx] = run;
            run += cnt[idx];
        }
    }
    if (t == SCAN_T - 1) rowptr[N_NODES] = part[t];
}

__global__ void scatter_edges(const int* __restrict__ ei,
                              const int* __restrict__ rowptr,
                              int* __restrict__ fill,
                              int* __restrict__ esrc)
{
    int e = blockIdx.x * blockDim.x + threadIdx.x;
    if (e < N_EDGES) {
        int d = ei[N_EDGES + e];
        int pos = rowptr[d] + atomicAdd(&fill[d], 1);
        esrc[pos] = ei[e];
    }
}

// ---------------- W pre-swizzle into MFMA B-fragment order ----------------
// Wsw linear idx = layer*65536 + m*16384 + ct*2048 + ks*512 + lane*8 + j
// value = W_m[layer][k = ks*32 + (lane>>4)*8 + j][col = ct*16 + (lane&15)]
__global__ void convert_wsw(const float* __restrict__ Wq, const float* __restrict__ Wk,
                            const float* __restrict__ Wv, const float* __restrict__ Wsk,
                            __half* __restrict__ Wsw)
{
    int t = blockIdx.x * blockDim.x + threadIdx.x;
    if (t >= LAYERS * 4 * 16384) return;
    int j    = t & 7;
    int lane = (t >> 3) & 63;
    int ks   = (t >> 9) & 3;
    int ct   = (t >> 11) & 7;
    int m    = (t >> 14) & 3;
    int layer = t >> 16;
    const float* W = (m == 0) ? Wq : (m == 1) ? Wk : (m == 2) ? Wv : Wsk;
    int k   = ks * 32 + (lane >> 4) * 8 + j;
    int col = ct * 16 + (lane & 15);
    Wsw[t] = __float2half(W[(long)layer * 16384 + k * 128 + col]);
}

// ---------------- MFMA fused 4-matrix GEMM ----------------
// 64 rows/block, 4 waves; wave w owns rows 16w..16w+15, all 128 cols.
// A: x tile staged fp16 in LDS (pad 136 -> 2-way-free banks).
// B: pre-swizzled Wsw, one coalesced 16B load per lane per (ct,ks).
// D layout (verified m89/m91): col=lane&15, row=(lane>>4)*4+reg.
// q (m0), skip (m3): fp32 direct stores (64B segments).
// k (m1), v (m2): fp16 via epi LDS -> coalesced uint4 stores.
// kv layout: [N][256] halfs, k cols 0..127, v cols 128..255.
__global__ __launch_bounds__(256) void gemm4_mfma(
    const float* __restrict__ x,
    const __half* __restrict__ Wsw,   // layer-offset applied by caller
    const float* __restrict__ bq, const float* __restrict__ bk,
    const float* __restrict__ bv, const float* __restrict__ bsk,
    float* __restrict__ oq, __half* __restrict__ okv, float* __restrict__ osk)
{
    __shared__ _Float16 xh[64][136];
    __shared__ _Float16 epi[64][136];
    const int tid = threadIdx.x;
    const int bRow = blockIdx.x * 64;

    // stage x -> fp16 LDS
    #pragma unroll
    for (int t = 0; t < 8; ++t) {
        int i = tid + t * 256;
        int r = i >> 5, c4 = i & 31;
        int gr = bRow + r;
        float4 val = make_float4(0.f, 0.f, 0.f, 0.f);
        if (gr < N_NODES)
            val = *reinterpret_cast<const float4*>(x + (long)gr * HC + c4 * 4);
        _Float16* d = &xh[r][c4 * 4];
        d[0] = (_Float16)val.x; d[1] = (_Float16)val.y;
        d[2] = (_Float16)val.z; d[3] = (_Float16)val.w;
    }
    __syncthreads();

    const int w = tid >> 6;
    const int lane = tid & 63;
    const int arow = lane & 15;     // A row / D col / B col
    const int kgrp = lane >> 4;     // k-group / D row-group

    half8 A[4];
    #pragma unroll
    for (int ks = 0; ks < 4; ++ks)
        A[ks] = *reinterpret_cast<const half8*>(&xh[16 * w + arow][ks * 32 + kgrp * 8]);

    const half8* Wf = reinterpret_cast<const half8*>(Wsw);
    const float* bm[4] = {bq, bk, bv, bsk};

    for (int m = 0; m < 4; ++m) {
        const float* __restrict__ bias = bm[m];
        for (int ct = 0; ct < 8; ++ct) {
            float bz = bias[ct * 16 + arow];
            f32x4 acc = {bz, bz, bz, bz};
            #pragma unroll
            for (int ks = 0; ks < 4; ++ks) {
                half8 B = Wf[((m * 8 + ct) * 4 + ks) * 64 + lane];
                acc = __builtin_amdgcn_mfma_f32_16x16x32_f16(A[ks], B, acc, 0, 0, 0);
            }
            if (m == 0 || m == 3) {
                float* o = (m == 0) ? oq : osk;
                #pragma unroll
                for (int r4 = 0; r4 < 4; ++r4) {
                    int gr = bRow + 16 * w + kgrp * 4 + r4;
                    if (gr < N_NODES) o[(long)gr * HC + ct * 16 + arow] = acc[r4];
                }
            } else {
                #pragma unroll
                for (int r4 = 0; r4 < 4; ++r4)
                    epi[16 * w + kgrp * 4 + r4][ct * 16 + arow] = (_Float16)acc[r4];
            }
        }
        if (m == 1 || m == 2) {
            __syncthreads();
            const int koff = (m == 1) ? 0 : 128;
            #pragma unroll
            for (int t2 = 0; t2 < 4; ++t2) {
                int i = tid + t2 * 256;
                int r = i >> 4, c8 = i & 15;
                int gr = bRow + r;
                if (gr < N_NODES) {
                    uint4 dd = *reinterpret_cast<const uint4*>(&epi[r][c8 * 8]);
                    *reinterpret_cast<uint4*>(okv + (long)gr * 256 + koff + c8 * 8) = dd;
                }
            }
            __syncthreads();
        }
    }
}

// ---------------- fused attention: logits + softmax + aggregate + skip + relu
// One wave per dst node. Lane l owns channel pair (2l, 2l+1), head = l>>4.
// kv fp16 [N][256]: k cols 0..127, v cols 128..255; two half2 loads/edge/lane.
__global__ __launch_bounds__(256) void edge_attn(
    const float* __restrict__ q, const __half* __restrict__ kv,
    const float* __restrict__ skip,
    const int* __restrict__ rowptr, const int* __restrict__ esrc,
    float* __restrict__ xout)
{
    const int lane = threadIdx.x & 63;
    const int node = (int)(((long)blockIdx.x * blockDim.x + threadIdx.x) >> 6);
    if (node >= N_NODES) return;
    const int beg = rowptr[node], end = rowptr[node + 1];
    const long qb = (long)node * HC;
    const float2 qp = *reinterpret_cast<const float2*>(q + qb + 2 * lane);
    const float scale = 0.17677669529663687f;  // 1/sqrt(32)

    float accx = 0.f, accy = 0.f, ps = 0.f;
    int pos = beg;
    for (; pos + 6 <= end; pos += 6) {
        float2 kf[6], vf[6];
        #pragma unroll
        for (int u = 0; u < 6; ++u) {
            const __half2* rp = reinterpret_cast<const __half2*>(kv + (long)esrc[pos + u] * 256);
            kf[u] = __half22float2(rp[lane]);
            vf[u] = __half22float2(rp[64 + lane]);
        }
        float a[6];
        #pragma unroll
        for (int u = 0; u < 6; ++u) a[u] = qp.x * kf[u].x + qp.y * kf[u].y;
        #pragma unroll
        for (int m = 1; m <= 8; m <<= 1) {
            #pragma unroll
            for (int u = 0; u < 6; ++u) a[u] += __shfl_xor(a[u], m, 64);
        }
        #pragma unroll
        for (int u = 0; u < 6; ++u) {
            float p = __expf(a[u] * scale);
            accx += p * vf[u].x;
            accy += p * vf[u].y;
            ps += p;
        }
    }
    for (; pos < end; ++pos) {
        const __half2* rp = reinterpret_cast<const __half2*>(kv + (long)esrc[pos] * 256);
        float2 kf = __half22float2(rp[lane]);
        float2 vv = __half22float2(rp[64 + lane]);
        float a0 = qp.x * kf.x + qp.y * kf.y;
        #pragma unroll
        for (int m = 1; m <= 8; m <<= 1) a0 += __shfl_xor(a0, m, 64);
        float p0 = __expf(a0 * scale);
        accx += p0 * vv.x;
        accy += p0 * vv.y;
        ps += p0;
    }
    const float inv = 1.f / (ps + 1e-16f);
    const float2 sk = *reinterpret_cast<const float2*>(skip + qb + 2 * lane);
    float r0 = accx * inv + sk.x;
    float r1 = accy * inv + sk.y;
    float2 res;
    res.x = r0 > 0.f ? r0 : 0.f;
    res.y = r1 > 0.f ? r1 : 0.f;
    *reinterpret_cast<float2*>(xout + qb + 2 * lane) = res;
}

// ---------------- global mean pool: chunked run-length reduction ---------
#define POOL_CHUNK 64
__global__ __launch_bounds__(128) void pool_sum2(
    const float* __restrict__ x, const int* __restrict__ batch,
    float* __restrict__ gsum, float* __restrict__ gcnt)
{
    const int c = threadIdx.x;            // 0..127 (channel)
    const int base = blockIdx.x * POOL_CHUNK;
    if (base >= N_NODES) return;
    const int end = min(base + POOL_CHUNK, N_NODES);
    float acc = 0.f;
    int cnt = 0;
    int curg = batch[base];
    for (int n = base; n < end; ++n) {
        int g = batch[n];
        if (g != curg) {
            atomicAdd(&gsum[curg * HC + c], acc);
            if (c == 0) atomicAdd(&gcnt[curg], (float)cnt);
            acc = 0.f; cnt = 0; curg = g;
        }
        acc += x[(long)n * HC + c];
        cnt++;
    }
    atomicAdd(&gsum[curg * HC + c], acc);
    if (c == 0) atomicAdd(&gcnt[curg], (float)cnt);
}

// ---------------- final FC ----------------
__global__ void final_fc(const float* __restrict__ gsum, const float* __restrict__ gcnt,
                         const float* __restrict__ fcW, const float* __restrict__ fcb,
                         float* __restrict__ out)
{
    int i = blockIdx.x * blockDim.x + threadIdx.x;
    if (i < NGRAPH * OUT_CH) {
        int g = i >> 6, o = i & 63;
        float cnt = gcnt[g];
        cnt = cnt > 1.f ? cnt : 1.f;
        float inv = 1.f / cnt;
        float accv = fcb[o];
        for (int c = 0; c < HC; ++c)
            accv += (gsum[g * HC + c] * inv) * fcW[c * OUT_CH + o];
        out[i] = accv;
    }
}

extern "C" void kernel_launch(void* const* d_in, const int* in_sizes, int n_in,
                              void* d_out, int out_size, void* d_ws, size_t ws_size,
                              hipStream_t stream)
{
    const float* x0   = (const float*)d_in[0];
    const int*   ei   = (const int*)d_in[1];
    const int*   batch= (const int*)d_in[2];
    const float* Wq   = (const float*)d_in[3];
    const float* bq   = (const float*)d_in[4];
    const float* Wk   = (const float*)d_in[5];
    const float* bk   = (const float*)d_in[6];
    const float* Wv   = (const float*)d_in[7];
    const float* bv   = (const float*)d_in[8];
    const float* Wsk  = (const float*)d_in[9];
    const float* bsk  = (const float*)d_in[10];
    const float* fcW  = (const float*)d_in[11];
    const float* fcb  = (const float*)d_in[12];
    float* out = (float*)d_out;

    const long NH = (long)N_NODES * HC;   // 6.4M floats
    float* ws   = (float*)d_ws;
    float* q    = ws;                    // NH floats
    float* skip = q + NH;                // NH floats
    float* xA   = skip + NH;             // NH floats
    float* gsum = xA + NH;               // G*HC
    float* gcnt = gsum + NGRAPH * HC;    // G
    __half* kvh = (__half*)(gcnt + NGRAPH);          // N*256 halfs (25.6 MB)
    __half* Wsw = kvh + (long)N_NODES * 256;         // 12*16384 halfs (393 KB)
    int*   iws  = (int*)(Wsw + (long)LAYERS * 4 * 16384);
    int*   rowptr = iws;                 // N+1
    int*   cnt    = rowptr + (N_NODES + 1);  // N (reused as fill)
    int*   esrc   = cnt + N_NODES;       // E

    const int gemmGrid = (N_NODES + 63) / 64;                     // 782
    const int eGrid    = (N_EDGES + 255) / 256;                   // 6250
    const int nodeGrid = (N_NODES + 3) / 4;                       // 12500 (4 waves/block)

    // ---- CSR build (edge_index is layer-invariant) ----
    zero_i32<<<256, 256, 0, stream>>>(cnt, N_NODES);
    hist_dst<<<eGrid, 256, 0, stream>>>(ei, cnt);
    scan_rowptr<<<1, SCAN_T, 0, stream>>>(cnt, rowptr);
    zero_i32<<<256, 256, 0, stream>>>(cnt, N_NODES);   // reuse as fill
    scatter_edges<<<eGrid, 256, 0, stream>>>(ei, rowptr, cnt, esrc);

    // ---- W pre-swizzle (all layers, once) ----
    convert_wsw<<<(LAYERS * 4 * 16384 + 255) / 256, 256, 0, stream>>>(Wq, Wk, Wv, Wsk, Wsw);

    // ---- layers ----
    const float* xin = x0;
    for (int l = 0; l < LAYERS; ++l) {
        const long bOff = (long)l * HC;
        gemm4_mfma<<<gemmGrid, 256, 0, stream>>>(xin, Wsw + (long)l * 65536,
            bq + bOff, bk + bOff, bv + bOff, bsk + bOff,
            q, kvh, skip);
        edge_attn<<<nodeGrid, 256, 0, stream>>>(q, kvh, skip, rowptr, esrc, xA);
        xin = xA;
    }

    // ---- pooling + fc ----
    zero_f32<<<64, 256, 0, stream>>>(gsum, (long)NGRAPH * HC + NGRAPH);
    pool_sum2<<<(N_NODES + POOL_CHUNK - 1) / POOL_CHUNK, 128, 0, stream>>>(xin, batch, gsum, gcnt);
    final_fc<<<(NGRAPH * OUT_CH + 255) / 256, 256, 0, stream>>>(gsum, gcnt, fcW, fcb, out);
}